// Round 11
// baseline (107.626 us; speedup 1.0000x reference)
//
#include <hip/hip_runtime.h>
#include <math.h>

#define IMG_H 512
#define IMG_W 512
#define PLANE (IMG_H * IMG_W)
#define NB 9
#define LSTR 264   // [0..2]pad [3]=Lhalo [4..259]=cols 0..255 [260]=Rhalo [261..263]pad

// Block = 8-row x 256-col half-band. Grid = 32 x 64 x 2 = 4096 blocks, 256 thr.
// Thread t owns local col t (8 pixels, row pairs hy/hy+4 for ILP).
// Bin accumulation: per-thread PRIVATE LDS slots via ds_add_f32 (single
// writer -> deterministic; stride 9 floats -> 2 lanes/bank = conflict-free),
// replacing the 27-VALU/pixel cndmask scatter.
//
// CORRECTNESS MODEL (do not change): decision chain bit-exact vs the fp32 ref:
//   gray  = ((c0+c1)+c2)/3.0f            (IEEE fp32 div)
//   gx,gy = Sobel, tap-lex order, +-1/+-2 (exact multiplies)
//   fast fp32 atan2 classifier (poly pre-scaled by 9/pi); within 2.5e-4 of
//   integer pb (incl. 0/NaN edges) fall back to exact
//   (float)atan2(fp64) -> /(float)pi*9 -> floored mod 9.
// nrm is NOT part of the decision -> raw v_sqrt_f32 is safe (continuous path).
__global__ __launch_bounds__(256, 8) void hog_kernel(const float* __restrict__ x,
                                                     float* __restrict__ out) {
    __shared__ float sgray[10 * LSTR];   // 10560 B
    __shared__ float sbins[256 * NB];    //  9216 B  (total 19776 B -> 8 blk/CU)

    const int t    = threadIdx.x;
    const int n    = blockIdx.x >> 7;
    const int r7   = blockIdx.x & 127;
    const int cy   = r7 >> 1;
    const int half = r7 & 1;
    const int h0   = cy * 8;
    const int wstart = half * 256;
    const float* xn = x + (size_t)n * 3 * PLANE;

    float* mybins = &sbins[t * NB];
#pragma unroll
    for (int b = 0; b < NB; b++) mybins[b] = 0.0f;   // own slots; no sync needed

    // halo cols (threads 0..19): row r, left->LDS idx 3, right->idx 260
    if (t < 20) {
        const int r    = t >> 1;
        const int side = t & 1;
        const int h    = h0 - 1 + r;
        const int col  = wstart - 1 + side * 257;
        float g = 0.0f;
        if ((unsigned)h < IMG_H && (unsigned)col < IMG_W) {
            const float* p = xn + (size_t)h * IMG_W + col;
            g = ((p[0] + p[PLANE]) + p[2 * PLANE]) / 3.0f;
        }
        sgray[r * LSTR + 3 + side * 257] = g;
    }
    // interior: 10 rows x 64 float4, aligned ds_write_b128 at idx 4 + 4*c4
#pragma unroll
    for (int k = 0; k < 3; k++) {
        const int i4 = t + k * 256;
        if (i4 < 640) {
            const int r  = i4 >> 6;
            const int c4 = i4 & 63;
            const int h  = h0 - 1 + r;
            float4 gv = make_float4(0.0f, 0.0f, 0.0f, 0.0f);
            if ((unsigned)h < IMG_H) {
                const float* p = xn + (size_t)h * IMG_W + wstart + 4 * c4;
                const float4 a = *(const float4*)(p);
                const float4 b = *(const float4*)(p + PLANE);
                const float4 c = *(const float4*)(p + 2 * PLANE);
                gv.x = ((a.x + b.x) + c.x) / 3.0f;
                gv.y = ((a.y + b.y) + c.y) / 3.0f;
                gv.z = ((a.z + b.z) + c.z) / 3.0f;
                gv.w = ((a.w + b.w) + c.w) / 3.0f;
            }
            *(float4*)&sgray[r * LSTR + 4 + 4 * c4] = gv;
        }
    }
    __syncthreads();

// classify + scatter: window rows RA,RB,RC -> two ds_add_f32 into private slots
#define PIXEL(RA, RB, RC)                                                        \
    {                                                                            \
        const float tl = RA[0], tc = RA[1], tr = RA[2];                          \
        const float ml = RB[0],             mr = RB[2];                          \
        const float bl = RC[0], bc = RC[1], br = RC[2];                          \
        const float gx = ((((tl - tr) + 2.0f * ml) - 2.0f * mr) + bl) - br;      \
        const float gy = ((((tl + 2.0f * tc) + tr) - bl) - 2.0f * bc) - br;      \
        const float s2 = fmaf(gx, gx, gy * gy);                                  \
        float nrm;                                                               \
        asm("v_sqrt_f32 %0, %1" : "=v"(nrm) : "v"(s2));  /* continuous path */   \
        const float fa = fabsf(gx), fb = fabsf(gy);                              \
        const float mn = fminf(fa, fb), mx = fmaxf(fa, fb);                      \
        float rcpmx;                                                             \
        asm("v_rcp_f32 %0, %1" : "=v"(rcpmx) : "v"(mx));                         \
        const float tt = mn * rcpmx;            /* mx==0 -> NaN -> slow */       \
        const float ss = tt * tt;                                                \
        float po = fmaf(ss, -0.03357890f, 0.15084052f);                          \
        po = fmaf(ss, po, -0.33355581f);                                         \
        po = fmaf(ss, po, 0.55446223f);                                          \
        po = fmaf(ss, po, -0.95289958f);                                         \
        po = fmaf(ss, po, 2.86472384f);         /* poly pre-scaled by 9/pi */    \
        float u = tt * po;                                                       \
        if (fa > fb)    u = 4.5f - u;                                            \
        if (gy < 0.0f)  u = 9.0f - u;                                            \
        if (gx < 0.0f)  u = -u;                                                  \
        const float fl   = floorf(u);                                            \
        const float frac = u - fl;                                               \
        const float dist = fminf(frac, 1.0f - frac);                             \
        int lo, hi;                                                              \
        if (dist > 2.5e-4f) {                   /* NaN -> false -> slow */       \
            lo = (int)fl; if (lo < 0) lo += NB;                                  \
            hi = lo + 1;  if (hi == NB) hi = 0;                                  \
        } else {                                                                 \
            /* exact reference chain (bit-identical to rounds 2-10) */           \
            const float ph  = (float)atan2((double)gx, (double)gy);              \
            const float pbf = ph / (float)M_PI * 9.0f;                           \
            lo = (int)floorf(pbf) % NB; if (lo < 0) lo += NB;                    \
            hi = (int)ceilf(pbf)  % NB; if (hi < 0) hi += NB;                    \
        }                                                                        \
        atomicAdd(&mybins[lo], nrm);           /* ds_add_f32, private slot */    \
        atomicAdd(&mybins[hi], 1.0f - nrm);                                      \
    }

    // two rolling windows: chain A = rows 0..3, chain B = rows 4..7
    float raA[3], rbA[3], rcA[3], raB[3], rbB[3], rcB[3];
    {
        const float* p0 = &sgray[0 * LSTR + t];
        const float* p1 = &sgray[1 * LSTR + t];
        const float* p4 = &sgray[4 * LSTR + t];
        const float* p5 = &sgray[5 * LSTR + t];
        raA[0] = p0[3]; raA[1] = p0[4]; raA[2] = p0[5];
        rbA[0] = p1[3]; rbA[1] = p1[4]; rbA[2] = p1[5];
        raB[0] = p4[3]; raB[1] = p4[4]; raB[2] = p4[5];
        rbB[0] = p5[3]; rbB[1] = p5[4]; rbB[2] = p5[5];
    }

#pragma unroll
    for (int k = 0; k < 4; k++) {
        const float* pA = &sgray[(k + 2) * LSTR + t];
        const float* pB = &sgray[(k + 6) * LSTR + t];
        rcA[0] = pA[3]; rcA[1] = pA[4]; rcA[2] = pA[5];
        rcB[0] = pB[3]; rcB[1] = pB[4]; rcB[2] = pB[5];

        PIXEL(raA, rbA, rcA)
        PIXEL(raB, rbB, rcB)

#pragma unroll
        for (int q = 0; q < 3; q++) {
            raA[q] = rbA[q]; rbA[q] = rcA[q];
            raB[q] = rbB[q]; rbB[q] = rcB[q];
        }
    }
#undef PIXEL

    __syncthreads();

    // cell cc (local cols 8cc..8cc+7) gathers threads 8cc..8cc+7; fixed order
    for (int idx = t; idx < NB * 32; idx += 256) {
        const int b  = idx >> 5;
        const int cc = idx & 31;
        const int base = 8 * cc * NB + b;
        float s = sbins[base];
#pragma unroll
        for (int j = 1; j < 8; j++) s += sbins[base + j * NB];
        out[((size_t)n * NB + b) * 4096 + (size_t)cy * 64 + half * 32 + cc]
            = s * (1.0f / 64.0f);
    }
}

extern "C" void kernel_launch(void* const* d_in, const int* in_sizes, int n_in,
                              void* d_out, int out_size, void* d_ws, size_t ws_size,
                              hipStream_t stream) {
    const float* x = (const float*)d_in[0];
    float* out = (float*)d_out;
    hog_kernel<<<4096, 256, 0, stream>>>(x, out);
}

// Round 12
// 45.222 us; speedup vs baseline: 2.3799x; 2.3799x over previous
//
#include <hip/hip_runtime.h>
#include <math.h>

#define IMG_H 512
#define IMG_W 512
#define PLANE (IMG_H * IMG_W)
#define NB 9
#define LSTR 264   // [0..2]pad [3]=Lhalo [4..259]=cols 0..255 [260]=Rhalo [261..263]pad

// A/B ROUND: SCAT=0 (register mask scatter, r8 control) on images 0..15,
// SCAT=1 (non-atomic LDS read-modify-write scatter) on images 16..31.
// Both use the identical bit-exact decision chain -> correctness unaffected;
// per-dispatch rocprof rows are the A/B measurement.
//
// CORRECTNESS MODEL (do not change): decision chain bit-exact vs the fp32 ref:
//   gray  = ((c0+c1)+c2)/3.0f            (IEEE fp32 div)
//   gx,gy = Sobel, tap-lex order, +-1/+-2 (exact multiplies)  [ORDER FROZEN]
//   fast fp32 atan2 classifier (poly pre-scaled by 9/pi); within 2.5e-4 of
//   integer pb (incl. 0/NaN edges) fall back to exact
//   (float)atan2(fp64) -> /(float)pi*9 -> floored mod 9.
// nrm is continuous-path only -> raw v_sqrt_f32 safe (r11 passed with it).
// cheap-lo: u' = u<0 ? u+9 : u, lo = (int)floor(u'); the +9 rounding error
// (<=5e-7) is inside the 2.5e-4 guard, so fast-path decisions are unchanged.
template<int SCAT>
__global__ __launch_bounds__(256, 8) void hog_kernel(const float* __restrict__ x,
                                                     float* __restrict__ out,
                                                     int img_off) {
    __shared__ float sgray[10 * LSTR];   // 10560 B
    __shared__ float sbins[256 * NB];    //  9216 B (19776 B total -> 8 blk/CU)

    const int t    = threadIdx.x;
    const int n    = img_off + (blockIdx.x >> 7);
    const int r7   = blockIdx.x & 127;
    const int cy   = r7 >> 1;
    const int half = r7 & 1;
    const int h0   = cy * 8;
    const int wstart = half * 256;
    const float* xn = x + (size_t)n * 3 * PLANE;

    float* mybins = &sbins[t * NB];
    if (SCAT == 1) {
#pragma unroll
        for (int b = 0; b < NB; b++) mybins[b] = 0.0f;   // own slots only
    }

    // halo cols (threads 0..19): row r, left->LDS idx 3, right->idx 260
    if (t < 20) {
        const int r    = t >> 1;
        const int side = t & 1;
        const int h    = h0 - 1 + r;
        const int col  = wstart - 1 + side * 257;
        float g = 0.0f;
        if ((unsigned)h < IMG_H && (unsigned)col < IMG_W) {
            const float* p = xn + (size_t)h * IMG_W + col;
            g = ((p[0] + p[PLANE]) + p[2 * PLANE]) / 3.0f;
        }
        sgray[r * LSTR + 3 + side * 257] = g;
    }
    // interior: 10 rows x 64 float4, aligned ds_write_b128 at idx 4 + 4*c4
#pragma unroll
    for (int k = 0; k < 3; k++) {
        const int i4 = t + k * 256;
        if (i4 < 640) {
            const int r  = i4 >> 6;
            const int c4 = i4 & 63;
            const int h  = h0 - 1 + r;
            float4 gv = make_float4(0.0f, 0.0f, 0.0f, 0.0f);
            if ((unsigned)h < IMG_H) {
                const float* p = xn + (size_t)h * IMG_W + wstart + 4 * c4;
                const float4 a = *(const float4*)(p);
                const float4 b = *(const float4*)(p + PLANE);
                const float4 c = *(const float4*)(p + 2 * PLANE);
                gv.x = ((a.x + b.x) + c.x) / 3.0f;
                gv.y = ((a.y + b.y) + c.y) / 3.0f;
                gv.z = ((a.z + b.z) + c.z) / 3.0f;
                gv.w = ((a.w + b.w) + c.w) / 3.0f;
            }
            *(float4*)&sgray[r * LSTR + 4 + 4 * c4] = gv;
        }
    }
    __syncthreads();

    float bins[NB];
    if (SCAT == 0) {
#pragma unroll
        for (int b = 0; b < NB; b++) bins[b] = 0.0f;
    }

// classify: window rows RA,RB,RC -> L (lo bin), W0 (at L), W1 (at L+1 mod 9)
#define PIXEL(RA, RB, RC)                                                        \
    {                                                                            \
        const float tl = RA[0], tc = RA[1], tr = RA[2];                          \
        const float ml = RB[0],             mr = RB[2];                          \
        const float bl = RC[0], bc = RC[1], br = RC[2];                          \
        const float gx = ((((tl - tr) + 2.0f * ml) - 2.0f * mr) + bl) - br;      \
        const float gy = ((((tl + 2.0f * tc) + tr) - bl) - 2.0f * bc) - br;      \
        const float s2 = fmaf(gx, gx, gy * gy);                                  \
        float nrm;                                                               \
        asm("v_sqrt_f32 %0, %1" : "=v"(nrm) : "v"(s2));  /* continuous path */   \
        const float fa = fabsf(gx), fb = fabsf(gy);                              \
        const float mn = fminf(fa, fb), mx = fmaxf(fa, fb);                      \
        float rcpmx;                                                             \
        asm("v_rcp_f32 %0, %1" : "=v"(rcpmx) : "v"(mx));                         \
        const float tt = mn * rcpmx;            /* mx==0 -> NaN -> slow */       \
        const float ss = tt * tt;                                                \
        float po = fmaf(ss, -0.03357890f, 0.15084052f);                          \
        po = fmaf(ss, po, -0.33355581f);                                         \
        po = fmaf(ss, po, 0.55446223f);                                          \
        po = fmaf(ss, po, -0.95289958f);                                         \
        po = fmaf(ss, po, 2.86472384f);         /* poly pre-scaled by 9/pi */    \
        float u = tt * po;                                                       \
        if (fa > fb)    u = 4.5f - u;                                            \
        if (gy < 0.0f)  u = 9.0f - u;                                            \
        if (gx < 0.0f)  u = -u;                                                  \
        const float up   = (u < 0.0f) ? u + 9.0f : u;   /* [0,9); NaN-safe */    \
        const float fl   = floorf(up);                                           \
        const float frac = up - fl;                                              \
        const float dist = fminf(frac, 1.0f - frac);                             \
        int L; float W0, W1;                                                     \
        if (dist > 2.5e-4f) {                   /* NaN -> false -> slow */       \
            L = (int)fl; W0 = nrm; W1 = 1.0f - nrm;                              \
        } else {                                                                 \
            /* exact reference chain (bit-identical to rounds 2-11) */           \
            const float ph  = (float)atan2((double)gx, (double)gy);              \
            const float pbf = ph / (float)M_PI * 9.0f;                           \
            int lo = (int)floorf(pbf) % NB; if (lo < 0) lo += NB;                \
            int hi = (int)ceilf(pbf)  % NB; if (hi < 0) hi += NB;                \
            L = lo;                                                              \
            if (lo == hi) { W0 = nrm + (1.0f - nrm); W1 = 0.0f; }                \
            else          { W0 = nrm; W1 = 1.0f - nrm; }                         \
        }                                                                        \
        if (SCAT == 0) {                                                         \
            bool m[NB];                                                          \
            _Pragma("unroll") for (int b = 0; b < NB; b++) m[b] = (L == b);      \
            _Pragma("unroll") for (int b = 0; b < NB; b++) {                     \
                const int bp = (b + 8) % 9;                                      \
                bins[b] += (m[b] ? W0 : (m[bp] ? W1 : 0.0f));                    \
            }                                                                    \
        } else {                                                                 \
            mybins[L] += W0;                    /* ds_read+add+ds_write */       \
            int h1 = L + 1; if (h1 == NB) h1 = 0;                                \
            mybins[h1] += W1;                   /* W1==0 on folded slow path */  \
        }                                                                        \
    }

    // two rolling windows: chain A = rows 0..3, chain B = rows 4..7
    float raA[3], rbA[3], rcA[3], raB[3], rbB[3], rcB[3];
    {
        const float* p0 = &sgray[0 * LSTR + t];
        const float* p1 = &sgray[1 * LSTR + t];
        const float* p4 = &sgray[4 * LSTR + t];
        const float* p5 = &sgray[5 * LSTR + t];
        raA[0] = p0[3]; raA[1] = p0[4]; raA[2] = p0[5];
        rbA[0] = p1[3]; rbA[1] = p1[4]; rbA[2] = p1[5];
        raB[0] = p4[3]; raB[1] = p4[4]; raB[2] = p4[5];
        rbB[0] = p5[3]; rbB[1] = p5[4]; rbB[2] = p5[5];
    }

#pragma unroll
    for (int k = 0; k < 4; k++) {
        const float* pA = &sgray[(k + 2) * LSTR + t];
        const float* pB = &sgray[(k + 6) * LSTR + t];
        rcA[0] = pA[3]; rcA[1] = pA[4]; rcA[2] = pA[5];
        rcB[0] = pB[3]; rcB[1] = pB[4]; rcB[2] = pB[5];

        PIXEL(raA, rbA, rcA)
        PIXEL(raB, rbB, rcB)

#pragma unroll
        for (int q = 0; q < 3; q++) {
            raA[q] = rbA[q]; rbA[q] = rcA[q];
            raB[q] = rbB[q]; rbB[q] = rcB[q];
        }
    }
#undef PIXEL

    if (SCAT == 0) {
#pragma unroll
        for (int b = 0; b < NB; b++) mybins[b] = bins[b];
    }
    __syncthreads();

    // cell cc (local cols 8cc..8cc+7) gathers threads 8cc..8cc+7; fixed order
    for (int idx = t; idx < NB * 32; idx += 256) {
        const int b  = idx >> 5;
        const int cc = idx & 31;
        const int base = 8 * cc * NB + b;
        float s = sbins[base];
#pragma unroll
        for (int j = 1; j < 8; j++) s += sbins[base + j * NB];
        out[((size_t)n * NB + b) * 4096 + (size_t)cy * 64 + half * 32 + cc]
            = s * (1.0f / 64.0f);
    }
}

extern "C" void kernel_launch(void* const* d_in, const int* in_sizes, int n_in,
                              void* d_out, int out_size, void* d_ws, size_t ws_size,
                              hipStream_t stream) {
    const float* x = (const float*)d_in[0];
    float* out = (float*)d_out;
    // A/B: images 0..15 with register scatter, 16..31 with LDS RMW scatter.
    hog_kernel<0><<<2048, 256, 0, stream>>>(x, out, 0);
    hog_kernel<1><<<2048, 256, 0, stream>>>(x, out, 16);
}

// Round 13
// 38.446 us; speedup vs baseline: 2.7994x; 1.1763x over previous
//
#include <hip/hip_runtime.h>
#include <math.h>

#define IMG_H 512
#define IMG_W 512
#define PLANE (IMG_H * IMG_W)
#define NB 9
#define LSTR 264   // [0..2]pad [3]=Lhalo [4..259]=cols 0..255 [260]=Rhalo [261..263]pad

typedef __attribute__((ext_vector_type(2))) float f32x2;

// Block = 8-row x 256-col half-band. Grid = 32 x 64 x 2 = 4096 blocks, 256 thr.
// Thread t owns local col t (8 px, row pairs hy/hy+4 = chains A/B).
// Bins: f32x2 accumulators (lane .x = chain A, .y = chain B) updated with
// packed v_pk_fma_f32 -> one instruction covers both pixels per bin.
// __launch_bounds__(256,4): 128-VGPR budget so the allocator interleaves the
// A/B chains instead of serializing at 28 VGPR (r8-r12 behavior).
//
// CORRECTNESS MODEL (do not change): decision chain bit-exact vs the fp32 ref:
//   gray  = ((c0+c1)+c2)/3.0f            (IEEE fp32 div)
//   gx,gy = Sobel, tap-lex order, +-1/+-2 (exact multiplies)  [ORDER FROZEN]
//   fast fp32 atan2 classifier (poly pre-scaled by 9/pi); within 2.5e-4 of
//   integer pb (incl. 0/NaN edges) fall back to exact
//   (float)atan2(fp64) -> /(float)pi*9 -> floored mod 9.
// nrm is continuous-path only -> raw v_sqrt_f32 safe.
// cheap-lo: u' = u<0 ? u+9 : u (rounding <=5e-7, inside the guard).
__global__ __launch_bounds__(256, 4) void hog_kernel(const float* __restrict__ x,
                                                     float* __restrict__ out) {
    __shared__ float sgray[10 * LSTR];   // 10560 B
    __shared__ float sbins[256 * NB];    //  9216 B

    const int t    = threadIdx.x;
    const int n    = blockIdx.x >> 7;
    const int r7   = blockIdx.x & 127;
    const int cy   = r7 >> 1;
    const int half = r7 & 1;
    const int h0   = cy * 8;
    const int wstart = half * 256;
    const float* xn = x + (size_t)n * 3 * PLANE;

    // halo cols (threads 0..19): row r, left->LDS idx 3, right->idx 260
    if (t < 20) {
        const int r    = t >> 1;
        const int side = t & 1;
        const int h    = h0 - 1 + r;
        const int col  = wstart - 1 + side * 257;
        float g = 0.0f;
        if ((unsigned)h < IMG_H && (unsigned)col < IMG_W) {
            const float* p = xn + (size_t)h * IMG_W + col;
            g = ((p[0] + p[PLANE]) + p[2 * PLANE]) / 3.0f;
        }
        sgray[r * LSTR + 3 + side * 257] = g;
    }
    // interior: 10 rows x 64 float4, aligned ds_write_b128 at idx 4 + 4*c4
#pragma unroll
    for (int k = 0; k < 3; k++) {
        const int i4 = t + k * 256;
        if (i4 < 640) {
            const int r  = i4 >> 6;
            const int c4 = i4 & 63;
            const int h  = h0 - 1 + r;
            float4 gv = make_float4(0.0f, 0.0f, 0.0f, 0.0f);
            if ((unsigned)h < IMG_H) {
                const float* p = xn + (size_t)h * IMG_W + wstart + 4 * c4;
                const float4 a = *(const float4*)(p);
                const float4 b = *(const float4*)(p + PLANE);
                const float4 c = *(const float4*)(p + 2 * PLANE);
                gv.x = ((a.x + b.x) + c.x) / 3.0f;
                gv.y = ((a.y + b.y) + c.y) / 3.0f;
                gv.z = ((a.z + b.z) + c.z) / 3.0f;
                gv.w = ((a.w + b.w) + c.w) / 3.0f;
            }
            *(float4*)&sgray[r * LSTR + 4 + 4 * c4] = gv;
        }
    }
    __syncthreads();

// classify: window rows RA,RB,RC -> L (lo bin), W0 (at L), W1 (at (L+1)%9)
#define PIXEL(RA, RB, RC, L, W0, W1)                                             \
    {                                                                            \
        const float tl = RA[0], tc = RA[1], tr = RA[2];                          \
        const float ml = RB[0],             mr = RB[2];                          \
        const float bl = RC[0], bc = RC[1], br = RC[2];                          \
        const float gx = ((((tl - tr) + 2.0f * ml) - 2.0f * mr) + bl) - br;      \
        const float gy = ((((tl + 2.0f * tc) + tr) - bl) - 2.0f * bc) - br;      \
        const float s2 = fmaf(gx, gx, gy * gy);                                  \
        float nrm;                                                               \
        asm("v_sqrt_f32 %0, %1" : "=v"(nrm) : "v"(s2));  /* continuous path */   \
        const float fa = fabsf(gx), fb = fabsf(gy);                              \
        const float mn = fminf(fa, fb), mx = fmaxf(fa, fb);                      \
        float rcpmx;                                                             \
        asm("v_rcp_f32 %0, %1" : "=v"(rcpmx) : "v"(mx));                         \
        const float tt = mn * rcpmx;            /* mx==0 -> NaN -> slow */       \
        const float ss = tt * tt;                                                \
        float po = fmaf(ss, -0.03357890f, 0.15084052f);                          \
        po = fmaf(ss, po, -0.33355581f);                                         \
        po = fmaf(ss, po, 0.55446223f);                                          \
        po = fmaf(ss, po, -0.95289958f);                                         \
        po = fmaf(ss, po, 2.86472384f);         /* poly pre-scaled by 9/pi */    \
        float u = tt * po;                                                       \
        if (fa > fb)    u = 4.5f - u;                                            \
        if (gy < 0.0f)  u = 9.0f - u;                                            \
        if (gx < 0.0f)  u = -u;                                                  \
        const float up   = (u < 0.0f) ? u + 9.0f : u;   /* [0,9); NaN-safe */    \
        const float fl   = floorf(up);                                           \
        const float frac = up - fl;                                              \
        const float dist = fminf(frac, 1.0f - frac);                             \
        if (dist > 2.5e-4f) {                   /* NaN -> false -> slow */       \
            L = (int)fl; W0 = nrm; W1 = 1.0f - nrm;                              \
        } else {                                                                 \
            /* exact reference chain (bit-identical to rounds 2-12) */           \
            const float ph  = (float)atan2((double)gx, (double)gy);              \
            const float pbf = ph / (float)M_PI * 9.0f;                           \
            int lo = (int)floorf(pbf) % NB; if (lo < 0) lo += NB;                \
            int hi = (int)ceilf(pbf)  % NB; if (hi < 0) hi += NB;                \
            L = lo;                                                              \
            if (lo == hi) { W0 = nrm + (1.0f - nrm); W1 = 0.0f; }                \
            else          { W0 = nrm; W1 = 1.0f - nrm; }                         \
        }                                                                        \
    }

    f32x2 bins2[NB];
#pragma unroll
    for (int b = 0; b < NB; b++) bins2[b] = (f32x2){0.0f, 0.0f};

    // two rolling windows: chain A = rows 0..3, chain B = rows 4..7
    float raA[3], rbA[3], rcA[3], raB[3], rbB[3], rcB[3];
    {
        const float* p0 = &sgray[0 * LSTR + t];
        const float* p1 = &sgray[1 * LSTR + t];
        const float* p4 = &sgray[4 * LSTR + t];
        const float* p5 = &sgray[5 * LSTR + t];
        raA[0] = p0[3]; raA[1] = p0[4]; raA[2] = p0[5];
        rbA[0] = p1[3]; rbA[1] = p1[4]; rbA[2] = p1[5];
        raB[0] = p4[3]; raB[1] = p4[4]; raB[2] = p4[5];
        rbB[0] = p5[3]; rbB[1] = p5[4]; rbB[2] = p5[5];
    }

#pragma unroll
    for (int k = 0; k < 4; k++) {
        const float* pA = &sgray[(k + 2) * LSTR + t];
        const float* pB = &sgray[(k + 6) * LSTR + t];
        rcA[0] = pA[3]; rcA[1] = pA[4]; rcA[2] = pA[5];
        rcB[0] = pB[3]; rcB[1] = pB[4]; rcB[2] = pB[5];

        int LA, LB; float W0A, W1A, W0B, W1B;
        PIXEL(raA, rbA, rcA, LA, W0A, W1A)
        PIXEL(raB, rbB, rcB, LB, W0B, W1B)

        const f32x2 w0 = (f32x2){W0A, W0B};
        const f32x2 w1 = (f32x2){W1A, W1B};
        f32x2 sel[NB];
#pragma unroll
        for (int b = 0; b < NB; b++)
            sel[b] = (f32x2){(LA == b) ? 1.0f : 0.0f, (LB == b) ? 1.0f : 0.0f};
#pragma unroll
        for (int b = 0; b < NB; b++)
            bins2[b] += sel[b] * w0;                 // v_pk_fma_f32 (A,B)
#pragma unroll
        for (int b = 0; b < NB; b++)
            bins2[b] += sel[(b + 8) % 9] * w1;       // W1 lands at L+1 mod 9

#pragma unroll
        for (int q = 0; q < 3; q++) {
            raA[q] = rbA[q]; rbA[q] = rcA[q];
            raB[q] = rbB[q]; rbB[q] = rcB[q];
        }
    }
#undef PIXEL

    float* mybins = &sbins[t * NB];
#pragma unroll
    for (int b = 0; b < NB; b++) mybins[b] = bins2[b].x + bins2[b].y;
    __syncthreads();

    // cell cc (local cols 8cc..8cc+7) gathers threads 8cc..8cc+7; fixed order
    for (int idx = t; idx < NB * 32; idx += 256) {
        const int b  = idx >> 5;
        const int cc = idx & 31;
        const int base = 8 * cc * NB + b;
        float s = sbins[base];
#pragma unroll
        for (int j = 1; j < 8; j++) s += sbins[base + j * NB];
        out[((size_t)n * NB + b) * 4096 + (size_t)cy * 64 + half * 32 + cc]
            = s * (1.0f / 64.0f);
    }
}

extern "C" void kernel_launch(void* const* d_in, const int* in_sizes, int n_in,
                              void* d_out, int out_size, void* d_ws, size_t ws_size,
                              hipStream_t stream) {
    const float* x = (const float*)d_in[0];
    float* out = (float*)d_out;
    hog_kernel<<<4096, 256, 0, stream>>>(x, out);
}

// Round 14
// 34.026 us; speedup vs baseline: 3.1630x; 1.1299x over previous
//
#include <hip/hip_runtime.h>
#include <math.h>

#define IMG_H 512
#define IMG_W 512
#define PLANE (IMG_H * IMG_W)
#define NB 9
#define LSTR 264   // [0..2]pad [3]=Lhalo [4..259]=cols 0..255 [260]=Rhalo [261..263]pad

typedef __attribute__((ext_vector_type(2))) float f32x2;

// Markstein constant-division: bit-identical to IEEE s/3.0f for normal s.
// y0 = RN(1/3); q = RN(s*y0); r = s - 3q (exact via FMA); q' = RN(q + r*y0).
// Markstein's final-iteration theorem (round-to-nearest, exact-FMA residual,
// correctly-rounded reciprocal seed) => q' = RN(s/3). 3 instr vs ~9 for the
// compiler's div_scale/div_fmas/div_fixup sequence.
__device__ __forceinline__ float div3(float s) {
    const float y0 = 0.33333334f;            // 0x3EAAAAAB = RN(1/3)
    const float q  = s * y0;
    const float r  = fmaf(-3.0f, q, s);      // exact residual
    return fmaf(r, y0, q);
}

// Block = 8-row x 256-col half-band. Grid = 32 x 64 x 2 = 4096 blocks, 256 thr.
// Thread t owns local col t (8 px, row pairs hy/hy+4 = chains A/B).
// Bins: f32x2 accumulators (x = chain A, y = chain B), packed v_pk_fma_f32.
//
// CORRECTNESS MODEL (do not change): decision chain bit-exact vs the fp32 ref:
//   gray  = ((c0+c1)+c2)/3.0f            (IEEE fp32 div == div3(), Markstein)
//   gx,gy = Sobel, tap-lex order, +-1/+-2 (exact multiplies)  [ORDER FROZEN]
//   fast fp32 atan2 classifier (poly pre-scaled by 9/pi, total decision error
//   < 4.5e-5 pb); within 1.2e-4 of integer pb (incl. 0/NaN edges) fall back
//   to exact (float)atan2(fp64) -> /(float)pi*9 -> floored mod 9.
//   Guard margin >= 2.5x the fast-chain error bound.
// nrm is continuous-path only -> raw v_sqrt_f32 safe.
// cheap-lo: u' = u<0 ? u+9 : u (rounding <=5e-7, inside the guard).
__global__ __launch_bounds__(256, 4) void hog_kernel(const float* __restrict__ x,
                                                     float* __restrict__ out) {
    __shared__ float sgray[10 * LSTR];   // 10560 B
    __shared__ float sbins[256 * NB];    //  9216 B

    const int t    = threadIdx.x;
    const int n    = blockIdx.x >> 7;
    const int r7   = blockIdx.x & 127;
    const int cy   = r7 >> 1;
    const int half = r7 & 1;
    const int h0   = cy * 8;
    const int wstart = half * 256;
    const float* xn = x + (size_t)n * 3 * PLANE;

    // halo cols (threads 0..19): row r, left->LDS idx 3, right->idx 260
    if (t < 20) {
        const int r    = t >> 1;
        const int side = t & 1;
        const int h    = h0 - 1 + r;
        const int col  = wstart - 1 + side * 257;
        float g = 0.0f;
        if ((unsigned)h < IMG_H && (unsigned)col < IMG_W) {
            const float* p = xn + (size_t)h * IMG_W + col;
            g = div3((p[0] + p[PLANE]) + p[2 * PLANE]);
        }
        sgray[r * LSTR + 3 + side * 257] = g;
    }
    // interior: 10 rows x 64 float4, aligned ds_write_b128 at idx 4 + 4*c4
#pragma unroll
    for (int k = 0; k < 3; k++) {
        const int i4 = t + k * 256;
        if (i4 < 640) {
            const int r  = i4 >> 6;
            const int c4 = i4 & 63;
            const int h  = h0 - 1 + r;
            float4 gv = make_float4(0.0f, 0.0f, 0.0f, 0.0f);
            if ((unsigned)h < IMG_H) {
                const float* p = xn + (size_t)h * IMG_W + wstart + 4 * c4;
                const float4 a = *(const float4*)(p);
                const float4 b = *(const float4*)(p + PLANE);
                const float4 c = *(const float4*)(p + 2 * PLANE);
                gv.x = div3((a.x + b.x) + c.x);
                gv.y = div3((a.y + b.y) + c.y);
                gv.z = div3((a.z + b.z) + c.z);
                gv.w = div3((a.w + b.w) + c.w);
            }
            *(float4*)&sgray[r * LSTR + 4 + 4 * c4] = gv;
        }
    }
    __syncthreads();

// classify: window rows RA,RB,RC -> L (lo bin), W0 (at L), W1 (at (L+1)%9)
#define PIXEL(RA, RB, RC, L, W0, W1)                                             \
    {                                                                            \
        const float tl = RA[0], tc = RA[1], tr = RA[2];                          \
        const float ml = RB[0],             mr = RB[2];                          \
        const float bl = RC[0], bc = RC[1], br = RC[2];                          \
        const float gx = ((((tl - tr) + 2.0f * ml) - 2.0f * mr) + bl) - br;      \
        const float gy = ((((tl + 2.0f * tc) + tr) - bl) - 2.0f * bc) - br;      \
        const float s2 = fmaf(gx, gx, gy * gy);                                  \
        float nrm;                                                               \
        asm("v_sqrt_f32 %0, %1" : "=v"(nrm) : "v"(s2));  /* continuous path */   \
        const float fa = fabsf(gx), fb = fabsf(gy);                              \
        const float mn = fminf(fa, fb), mx = fmaxf(fa, fb);                      \
        float rcpmx;                                                             \
        asm("v_rcp_f32 %0, %1" : "=v"(rcpmx) : "v"(mx));                         \
        const float tt = mn * rcpmx;            /* mx==0 -> NaN -> slow */       \
        const float ss = tt * tt;                                                \
        float po = fmaf(ss, -0.03357890f, 0.15084052f);                          \
        po = fmaf(ss, po, -0.33355581f);                                         \
        po = fmaf(ss, po, 0.55446223f);                                          \
        po = fmaf(ss, po, -0.95289958f);                                         \
        po = fmaf(ss, po, 2.86472384f);         /* poly pre-scaled by 9/pi */    \
        float u = tt * po;                                                       \
        if (fa > fb)    u = 4.5f - u;                                            \
        if (gy < 0.0f)  u = 9.0f - u;                                            \
        if (gx < 0.0f)  u = -u;                                                  \
        const float up   = (u < 0.0f) ? u + 9.0f : u;   /* [0,9); NaN-safe */    \
        const float fl   = floorf(up);                                           \
        const float frac = up - fl;                                              \
        const float dist = fminf(frac, 1.0f - frac);                             \
        if (dist > 1.2e-4f) {                   /* NaN -> false -> slow */       \
            L = (int)fl; W0 = nrm; W1 = 1.0f - nrm;                              \
        } else {                                                                 \
            /* exact reference chain (bit-identical to rounds 2-13) */           \
            const float ph  = (float)atan2((double)gx, (double)gy);              \
            const float pbf = ph / (float)M_PI * 9.0f;                           \
            int lo = (int)floorf(pbf) % NB; if (lo < 0) lo += NB;                \
            int hi = (int)ceilf(pbf)  % NB; if (hi < 0) hi += NB;                \
            L = lo;                                                              \
            if (lo == hi) { W0 = nrm + (1.0f - nrm); W1 = 0.0f; }                \
            else          { W0 = nrm; W1 = 1.0f - nrm; }                         \
        }                                                                        \
    }

    f32x2 bins2[NB];
#pragma unroll
    for (int b = 0; b < NB; b++) bins2[b] = (f32x2){0.0f, 0.0f};

    // two rolling windows: chain A = rows 0..3, chain B = rows 4..7
    float raA[3], rbA[3], rcA[3], raB[3], rbB[3], rcB[3];
    {
        const float* p0 = &sgray[0 * LSTR + t];
        const float* p1 = &sgray[1 * LSTR + t];
        const float* p4 = &sgray[4 * LSTR + t];
        const float* p5 = &sgray[5 * LSTR + t];
        raA[0] = p0[3]; raA[1] = p0[4]; raA[2] = p0[5];
        rbA[0] = p1[3]; rbA[1] = p1[4]; rbA[2] = p1[5];
        raB[0] = p4[3]; raB[1] = p4[4]; raB[2] = p4[5];
        rbB[0] = p5[3]; rbB[1] = p5[4]; rbB[2] = p5[5];
    }

#pragma unroll
    for (int k = 0; k < 4; k++) {
        const float* pA = &sgray[(k + 2) * LSTR + t];
        const float* pB = &sgray[(k + 6) * LSTR + t];
        rcA[0] = pA[3]; rcA[1] = pA[4]; rcA[2] = pA[5];
        rcB[0] = pB[3]; rcB[1] = pB[4]; rcB[2] = pB[5];

        int LA, LB; float W0A, W1A, W0B, W1B;
        PIXEL(raA, rbA, rcA, LA, W0A, W1A)
        PIXEL(raB, rbB, rcB, LB, W0B, W1B)

        const f32x2 w0 = (f32x2){W0A, W0B};
        const f32x2 w1 = (f32x2){W1A, W1B};
        f32x2 sel[NB];
#pragma unroll
        for (int b = 0; b < NB; b++)
            sel[b] = (f32x2){(LA == b) ? 1.0f : 0.0f, (LB == b) ? 1.0f : 0.0f};
#pragma unroll
        for (int b = 0; b < NB; b++)
            bins2[b] += sel[b] * w0;                 // v_pk_fma_f32 (A,B)
#pragma unroll
        for (int b = 0; b < NB; b++)
            bins2[b] += sel[(b + 8) % 9] * w1;       // W1 lands at L+1 mod 9

#pragma unroll
        for (int q = 0; q < 3; q++) {
            raA[q] = rbA[q]; rbA[q] = rcA[q];
            raB[q] = rbB[q]; rbB[q] = rcB[q];
        }
    }
#undef PIXEL

    float* mybins = &sbins[t * NB];
#pragma unroll
    for (int b = 0; b < NB; b++) mybins[b] = bins2[b].x + bins2[b].y;
    __syncthreads();

    // cell cc (local cols 8cc..8cc+7) gathers threads 8cc..8cc+7; fixed order
    for (int idx = t; idx < NB * 32; idx += 256) {
        const int b  = idx >> 5;
        const int cc = idx & 31;
        const int base = 8 * cc * NB + b;
        float s = sbins[base];
#pragma unroll
        for (int j = 1; j < 8; j++) s += sbins[base + j * NB];
        out[((size_t)n * NB + b) * 4096 + (size_t)cy * 64 + half * 32 + cc]
            = s * (1.0f / 64.0f);
    }
}

extern "C" void kernel_launch(void* const* d_in, const int* in_sizes, int n_in,
                              void* d_out, int out_size, void* d_ws, size_t ws_size,
                              hipStream_t stream) {
    const float* x = (const float*)d_in[0];
    float* out = (float*)d_out;
    hog_kernel<<<4096, 256, 0, stream>>>(x, out);
}

// Round 15
// 32.918 us; speedup vs baseline: 3.2696x; 1.0337x over previous
//
#include <hip/hip_runtime.h>
#include <math.h>

#define IMG_H 512
#define IMG_W 512
#define PLANE (IMG_H * IMG_W)
#define NB 9
#define LSTR 264   // [0..2]pad [3]=Lhalo [4..259]=cols 0..255 [260]=Rhalo [261..263]pad

typedef __attribute__((ext_vector_type(2))) float f32x2;

__device__ __forceinline__ f32x2 fma2(f32x2 a, f32x2 b, f32x2 c) {
    return __builtin_elementwise_fma(a, b, c);
}
__device__ __forceinline__ f32x2 splat2(float v) { return (f32x2){v, v}; }

// Markstein constant-division, packed: bit-identical to IEEE s/3.0f per lane.
__device__ __forceinline__ f32x2 div3x2(f32x2 s) {
    const f32x2 y0 = splat2(0.33333334f);      // RN(1/3)
    const f32x2 q  = s * y0;
    const f32x2 r  = fma2(splat2(-3.0f), q, s); // exact residual
    return fma2(r, y0, q);
}
__device__ __forceinline__ float div3(float s) {
    const float y0 = 0.33333334f;
    const float q  = s * y0;
    const float r  = fmaf(-3.0f, q, s);
    return fmaf(r, y0, q);
}

// Block = 8-row x 256-col half-band. Grid = 4096 x 256 thr. Thread t owns
// local col t; row pairs (hy, hy+4) = chains A/B processed PACKED (f32x2,
// VOP3P pk ops) through sobel/classifier arithmetic; scalar only where no
// packed op exists (sqrt/rcp/min/max/cndmask/floor/cvt).
//
// CORRECTNESS MODEL (do not change): decision chain bit-exact vs the fp32 ref:
//   gray  = ((c0+c1)+c2)/3.0f   (== div3, Markstein; packed == scalar per lane)
//   gx,gy = Sobel, tap-lex order, +-1/+-2 exact multiplies  [ORDER FROZEN;
//           fma contraction safe: multiplies exact -> single rounding either way]
//   fast classifier (err < 6e-5 pb-units); within 1.2e-4 of integer pb
//   (incl. 0/NaN/up==9 edges via d=up-rint(up)) fall back to exact
//   (float)atan2(fp64) -> /(float)pi*9 -> floored mod 9.
//   up = (sign(gx)^sign(gy)) ? 9-v : v ; L=(int)up (trunc==floor, fast path
//   excludes [9-1.2e-4, 9)). All rewrites bounded < guard.
__global__ __launch_bounds__(256, 4) void hog_kernel(const float* __restrict__ x,
                                                     float* __restrict__ out) {
    __shared__ float sgray[10 * LSTR];   // 10560 B
    __shared__ float sbins[256 * NB];    //  9216 B

    const int t    = threadIdx.x;
    const int n    = blockIdx.x >> 7;
    const int r7   = blockIdx.x & 127;
    const int cy   = r7 >> 1;
    const int half = r7 & 1;
    const int h0   = cy * 8;
    const int wstart = half * 256;
    const float* xn = x + (size_t)n * 3 * PLANE;

    // halo cols (threads 0..19): row r, left->LDS idx 3, right->idx 260
    if (t < 20) {
        const int r    = t >> 1;
        const int side = t & 1;
        const int h    = h0 - 1 + r;
        const int col  = wstart - 1 + side * 257;
        float g = 0.0f;
        if ((unsigned)h < IMG_H && (unsigned)col < IMG_W) {
            const float* p = xn + (size_t)h * IMG_W + col;
            g = div3((p[0] + p[PLANE]) + p[2 * PLANE]);
        }
        sgray[r * LSTR + 3 + side * 257] = g;
    }
    // interior: 10 rows x 64 float4, packed gray math, aligned ds_write_b128
#pragma unroll
    for (int k = 0; k < 3; k++) {
        const int i4 = t + k * 256;
        if (i4 < 640) {
            const int r  = i4 >> 6;
            const int c4 = i4 & 63;
            const int h  = h0 - 1 + r;
            float4 gv = make_float4(0.0f, 0.0f, 0.0f, 0.0f);
            if ((unsigned)h < IMG_H) {
                const float* p = xn + (size_t)h * IMG_W + wstart + 4 * c4;
                const float4 a = *(const float4*)(p);
                const float4 b = *(const float4*)(p + PLANE);
                const float4 c = *(const float4*)(p + 2 * PLANE);
                const f32x2* a2 = (const f32x2*)&a;
                const f32x2* b2 = (const f32x2*)&b;
                const f32x2* c2 = (const f32x2*)&c;
                const f32x2 g0 = div3x2((a2[0] + b2[0]) + c2[0]);
                const f32x2 g1 = div3x2((a2[1] + b2[1]) + c2[1]);
                gv = make_float4(g0.x, g0.y, g1.x, g1.y);
            }
            *(float4*)&sgray[r * LSTR + 4 + 4 * c4] = gv;
        }
    }
    __syncthreads();

// Packed dual-pixel classify: windows WA,WB,WC are f32x2 (x=chain A, y=chain B).
// Outputs LA,LB,W0A,W1A,W0B,W1B.
#define PIXEL2(WA, WB, WC, LA, LB, W0A, W1A, W0B, W1B)                           \
    {                                                                            \
        const f32x2 tl = WA[0], tcv = WA[1], tr = WA[2];                         \
        const f32x2 ml = WB[0],               mr = WB[2];                        \
        const f32x2 bl = WC[0], bcv = WC[1], br = WC[2];                         \
        const f32x2 gx = ((((tl - tr) + 2.0f * ml) - 2.0f * mr) + bl) - br;      \
        const f32x2 gy = ((((tl + 2.0f * tcv) + tr) - bl) - 2.0f * bcv) - br;    \
        const f32x2 s2v = fma2(gx, gx, gy * gy);                                 \
        float nA, nB;                                                            \
        { float sa = s2v.x, sb = s2v.y;                                          \
          asm("v_sqrt_f32 %0, %1" : "=v"(nA) : "v"(sa));                         \
          asm("v_sqrt_f32 %0, %1" : "=v"(nB) : "v"(sb)); }                       \
        const float faA = fabsf(gx.x), fbA = fabsf(gy.x);                        \
        const float faB = fabsf(gx.y), fbB = fabsf(gy.y);                        \
        const float mnA = fminf(faA, fbA), mxA = fmaxf(faA, fbA);                \
        const float mnB = fminf(faB, fbB), mxB = fmaxf(faB, fbB);                \
        float rA, rB;                                                            \
        asm("v_rcp_f32 %0, %1" : "=v"(rA) : "v"(mxA));                           \
        asm("v_rcp_f32 %0, %1" : "=v"(rB) : "v"(mxB));                           \
        const f32x2 tt = (f32x2){mnA, mnB} * (f32x2){rA, rB};                    \
        const f32x2 ssv = tt * tt;                                               \
        f32x2 po = fma2(ssv, splat2(-0.03357890f), splat2(0.15084052f));         \
        po = fma2(ssv, po, splat2(-0.33355581f));                                \
        po = fma2(ssv, po, splat2(0.55446223f));                                 \
        po = fma2(ssv, po, splat2(-0.95289958f));                                \
        po = fma2(ssv, po, splat2(2.86472384f));   /* pre-scaled by 9/pi */      \
        const f32x2 w   = tt * po;               /* [0, 2.25+eps] */             \
        const f32x2 w45 = splat2(4.5f) - w;                                      \
        const float vA = (faA > fbA) ? w45.x : w.x;                              \
        const float vB = (faB > fbB) ? w45.y : w.y;                              \
        const f32x2 vv = (f32x2){vA, vB};                                        \
        const f32x2 v9 = splat2(9.0f) - vv;                                      \
        const int sxA = (int)(__float_as_uint(gx.x) ^ __float_as_uint(gy.x));    \
        const int sxB = (int)(__float_as_uint(gx.y) ^ __float_as_uint(gy.y));    \
        const float upA = (sxA < 0) ? v9.x : vA;                                 \
        const float upB = (sxB < 0) ? v9.y : vB;                                 \
        const f32x2 up2 = (f32x2){upA, upB};                                     \
        const f32x2 rn2 = (f32x2){__builtin_rintf(upA), __builtin_rintf(upB)};   \
        const f32x2 d2  = up2 - rn2;                                             \
        if (fabsf(d2.x) > 1.2e-4f) {            /* NaN -> false -> slow */       \
            LA = (int)upA; W0A = nA; W1A = 1.0f - nA;                            \
        } else {                                                                 \
            /* exact reference chain (bit-identical to rounds 2-14) */           \
            const float ph  = (float)atan2((double)gx.x, (double)gy.x);          \
            const float pbf = ph / (float)M_PI * 9.0f;                           \
            int lo = (int)floorf(pbf) % NB; if (lo < 0) lo += NB;                \
            int hi = (int)ceilf(pbf)  % NB; if (hi < 0) hi += NB;                \
            LA = lo;                                                             \
            if (lo == hi) { W0A = nA + (1.0f - nA); W1A = 0.0f; }                \
            else          { W0A = nA; W1A = 1.0f - nA; }                         \
        }                                                                        \
        if (fabsf(d2.y) > 1.2e-4f) {                                             \
            LB = (int)upB; W0B = nB; W1B = 1.0f - nB;                            \
        } else {                                                                 \
            const float ph  = (float)atan2((double)gx.y, (double)gy.y);          \
            const float pbf = ph / (float)M_PI * 9.0f;                           \
            int lo = (int)floorf(pbf) % NB; if (lo < 0) lo += NB;                \
            int hi = (int)ceilf(pbf)  % NB; if (hi < 0) hi += NB;                \
            LB = lo;                                                             \
            if (lo == hi) { W0B = nB + (1.0f - nB); W1B = 0.0f; }                \
            else          { W0B = nB; W1B = 1.0f - nB; }                         \
        }                                                                        \
    }

    f32x2 bins2[NB];
#pragma unroll
    for (int b = 0; b < NB; b++) bins2[b] = splat2(0.0f);

    // packed rolling windows: .x = chain A (rows 0..3), .y = chain B (rows 4..7)
    f32x2 wa[3], wb[3], wc[3];
    {
        const float* p0 = &sgray[0 * LSTR + t];
        const float* p1 = &sgray[1 * LSTR + t];
        const float* p4 = &sgray[4 * LSTR + t];
        const float* p5 = &sgray[5 * LSTR + t];
#pragma unroll
        for (int i = 0; i < 3; i++) {
            wa[i] = (f32x2){p0[3 + i], p4[3 + i]};
            wb[i] = (f32x2){p1[3 + i], p5[3 + i]};
        }
    }

#pragma unroll
    for (int k = 0; k < 4; k++) {
        const float* pA = &sgray[(k + 2) * LSTR + t];
        const float* pB = &sgray[(k + 6) * LSTR + t];
#pragma unroll
        for (int i = 0; i < 3; i++) wc[i] = (f32x2){pA[3 + i], pB[3 + i]};

        int LA, LB; float W0A, W1A, W0B, W1B;
        PIXEL2(wa, wb, wc, LA, LB, W0A, W1A, W0B, W1B)

        const f32x2 w0 = (f32x2){W0A, W0B};
        const f32x2 w1 = (f32x2){W1A, W1B};
        f32x2 sel[NB];
#pragma unroll
        for (int b = 0; b < NB; b++)
            sel[b] = (f32x2){(LA == b) ? 1.0f : 0.0f, (LB == b) ? 1.0f : 0.0f};
#pragma unroll
        for (int b = 0; b < NB; b++)
            bins2[b] = fma2(sel[b], w0, bins2[b]);           // v_pk_fma_f32
#pragma unroll
        for (int b = 0; b < NB; b++)
            bins2[b] = fma2(sel[(b + 8) % 9], w1, bins2[b]); // W1 at L+1 mod 9

#pragma unroll
        for (int q = 0; q < 3; q++) { wa[q] = wb[q]; wb[q] = wc[q]; }
    }
#undef PIXEL2

    float* mybins = &sbins[t * NB];
#pragma unroll
    for (int b = 0; b < NB; b++) mybins[b] = bins2[b].x + bins2[b].y;
    __syncthreads();

    // cell cc (local cols 8cc..8cc+7) gathers threads 8cc..8cc+7; fixed order
    for (int idx = t; idx < NB * 32; idx += 256) {
        const int b  = idx >> 5;
        const int cc = idx & 31;
        const int base = 8 * cc * NB + b;
        float s = sbins[base];
#pragma unroll
        for (int j = 1; j < 8; j++) s += sbins[base + j * NB];
        out[((size_t)n * NB + b) * 4096 + (size_t)cy * 64 + half * 32 + cc]
            = s * (1.0f / 64.0f);
    }
}

extern "C" void kernel_launch(void* const* d_in, const int* in_sizes, int n_in,
                              void* d_out, int out_size, void* d_ws, size_t ws_size,
                              hipStream_t stream) {
    const float* x = (const float*)d_in[0];
    float* out = (float*)d_out;
    hog_kernel<<<4096, 256, 0, stream>>>(x, out);
}